// Round 1
// baseline (638.453 us; speedup 1.0000x reference)
//
#include <hip/hip_runtime.h>
#include <stdint.h>

#define N_PIX    65536
#define C_DIM    720
#define K_CLS    19
#define M_PROTO  10
#define NPROTO   190
#define CPAD     768
#define OFF_Q    12451840
#define OFF_PRED 24903680

typedef _Float16 half8 __attribute__((ext_vector_type(8)));
typedef float    f32x4 __attribute__((ext_vector_type(4)));

// ---- workspace layout (byte offsets) ----
#define WS_E       0u          // 192 floats
#define WS_G2      768u        // 192 floats
#define WS_G3      1536u       // 192 floats
#define WS_CNT     2304u       // 32 floats
#define WS_TIECNT  2432u       // 1 int
#define WS_V       2560u       // 192 floats
#define WS_PSCALE  4096u       // 65536 * float4
#define WS_EPIX    1052672u    // 65536*10 floats
#define WS_U       3674112u    // 65536 floats
#define WS_TIELIST 3936256u    // 65536 ints
#define WS_PF16    4198400u    // 192*768 half
#define WS_PF32    4493312u    // 190*720 float  (ends 5040512)

// ------------------------------------------------------------------
// zero the small accumulator region (E, G2, G3, cnt, tiecnt)
__global__ void zero_acc(float* ws) {
    if (threadIdx.x < 640) ws[threadIdx.x] = 0.f;
}

// ------------------------------------------------------------------
// L2-normalize prototypes -> f16 padded [192][768] and f32 [190][720]
__global__ void proto_prep(const float* __restrict__ protos,
                           _Float16* __restrict__ pf16,
                           float* __restrict__ pf32) {
    int p = blockIdx.x;
    int tid = threadIdx.x;
    if (p >= NPROTO) {   // padding rows 190,191 -> zeros
        for (int c = tid; c < CPAD; c += 256) pf16[(size_t)p * CPAD + c] = (_Float16)0.f;
        return;
    }
    __shared__ float red[256];
    const float* row = protos + (size_t)p * C_DIM;
    float ss = 0.f;
    for (int c = tid; c < C_DIM; c += 256) { float v = row[c]; ss += v * v; }
    red[tid] = ss;
    __syncthreads();
    for (int s = 128; s > 0; s >>= 1) {
        if (tid < s) red[tid] += red[tid + s];
        __syncthreads();
    }
    float invn = 1.f / fmaxf(sqrtf(red[0]), 1e-12f);
    for (int c = tid; c < CPAD; c += 256) {
        float v = (c < C_DIM) ? row[c] * invn : 0.f;
        pf16[(size_t)p * CPAD + c] = (_Float16)v;
        if (c < C_DIM) pf32[(size_t)p * C_DIM + c] = v;
    }
}

// ------------------------------------------------------------------
// LayerNorm + L2-norm statistics: per-pixel scalars (p, q, rn) such that
// xn_i = (p*x_i + q)*g_i + rn*b_i
__global__ void stats_kernel(const float* __restrict__ x,
                             const float* __restrict__ gamma,
                             const float* __restrict__ beta,
                             float4* __restrict__ pscale) {
    int wave = threadIdx.x >> 6, lane = threadIdx.x & 63;
    int n = blockIdx.x * 4 + wave;
    const float* row = x + (size_t)n * C_DIM;
    float a[8];
    #pragma unroll
    for (int t = 0; t < 8; ++t) a[t] = 0.f;
    #pragma unroll
    for (int j = 0; j < 12; ++j) {
        int i = lane + 64 * j;
        if (i < C_DIM) {
            float v = row[i], g = gamma[i], b = beta[i];
            float g2 = g * g;
            a[0] += v;          a[1] += v * v;
            a[2] += v * g2;     a[3] += v * v * g2;
            a[4] += v * g * b;  a[5] += g2;
            a[6] += g * b;      a[7] += b * b;
        }
    }
    #pragma unroll
    for (int m = 1; m < 64; m <<= 1) {
        #pragma unroll
        for (int t = 0; t < 8; ++t) a[t] += __shfl_xor(a[t], m);
    }
    if (lane == 0) {
        float mu   = a[0] * (1.f / 720.f);
        float var  = a[1] * (1.f / 720.f) - mu * mu;
        float rsig = rsqrtf(var + 1e-5f);
        float ny2  = rsig * rsig * (a[3] - 2.f * mu * a[2] + mu * mu * a[5])
                   + 2.f * rsig * (a[4] - mu * a[6]) + a[7];
        float rn   = 1.f / fmaxf(sqrtf(fmaxf(ny2, 0.f)), 1e-12f);
        float pp   = rsig * rn;
        pscale[n]  = make_float4(pp, -pp * mu, rn, 0.f);
    }
}

// ------------------------------------------------------------------
// Fused LN-apply + f16 MFMA GEMM: sim[n][m][k] = xn . protosN^T
// block = 128 pixels x 192 protos, wave = 32 pixels x 192 protos
__global__ __launch_bounds__(256) void gemm_sim(
        const float*  __restrict__ x,
        const float4* __restrict__ pscale,
        const float*  __restrict__ gamma,
        const float*  __restrict__ beta,
        const _Float16* __restrict__ pf16,
        float* __restrict__ out) {
    __shared__ _Float16 xs[128][72];
    __shared__ _Float16 ps[192][72];
    int tid = threadIdx.x;
    int wave = tid >> 6, lane = tid & 63;
    int lane15 = lane & 15, quad = lane >> 4;
    int n0 = blockIdx.x * 128;

    f32x4 acc[2][12];
    #pragma unroll
    for (int rt = 0; rt < 2; ++rt)
        #pragma unroll
        for (int ct = 0; ct < 12; ++ct)
            acc[rt][ct] = (f32x4){0.f, 0.f, 0.f, 0.f};

    #pragma unroll 1
    for (int ch = 0; ch < 12; ++ch) {
        __syncthreads();
        int kb4 = ch * 16;  // float4 index base within the 180 valid float4s
        // stage x (convert to normalized f16 on the fly)
        #pragma unroll
        for (int i = 0; i < 8; ++i) {
            int idx = tid + 256 * i;
            int r = idx >> 4, c4 = idx & 15;
            int gc4 = kb4 + c4;
            float4 xv = make_float4(0.f, 0.f, 0.f, 0.f);
            float4 gv = xv, bv = xv;
            if (gc4 < 180) {
                xv = *(const float4*)(x + (size_t)(n0 + r) * C_DIM + gc4 * 4);
                gv = *(const float4*)(gamma + gc4 * 4);
                bv = *(const float4*)(beta + gc4 * 4);
            }
            float4 sc = pscale[n0 + r];
            union { _Float16 h[4]; uint2 u; } cv;
            cv.h[0] = (_Float16)((sc.x * xv.x + sc.y) * gv.x + sc.z * bv.x);
            cv.h[1] = (_Float16)((sc.x * xv.y + sc.y) * gv.y + sc.z * bv.y);
            cv.h[2] = (_Float16)((sc.x * xv.z + sc.y) * gv.z + sc.z * bv.z);
            cv.h[3] = (_Float16)((sc.x * xv.w + sc.y) * gv.w + sc.z * bv.w);
            *reinterpret_cast<uint2*>(&xs[r][c4 * 4]) = cv.u;
        }
        // stage protos (already f16, padded)
        #pragma unroll
        for (int i = 0; i < 6; ++i) {
            int idx = tid + 256 * i;
            int r = idx >> 3, c8 = idx & 7;
            int4 v = *(const int4*)(pf16 + (size_t)r * CPAD + ch * 64 + c8 * 8);
            *reinterpret_cast<int4*>(&ps[r][c8 * 8]) = v;
        }
        __syncthreads();
        #pragma unroll
        for (int ks = 0; ks < 2; ++ks) {
            int col = ks * 32 + quad * 8;
            half8 a0 = *reinterpret_cast<const half8*>(&xs[wave * 32 + lane15][col]);
            half8 a1 = *reinterpret_cast<const half8*>(&xs[wave * 32 + 16 + lane15][col]);
            half8 b[12];
            #pragma unroll
            for (int ct = 0; ct < 12; ++ct)
                b[ct] = *reinterpret_cast<const half8*>(&ps[ct * 16 + lane15][col]);
            #pragma unroll
            for (int ct = 0; ct < 12; ++ct) {
                acc[0][ct] = __builtin_amdgcn_mfma_f32_16x16x32_f16(a0, b[ct], acc[0][ct], 0, 0, 0);
                acc[1][ct] = __builtin_amdgcn_mfma_f32_16x16x32_f16(a1, b[ct], acc[1][ct], 0, 0, 0);
            }
        }
    }
    // epilogue: C/D layout col=lane&15 (proto), row=quad*4+r (pixel)
    #pragma unroll
    for (int ct = 0; ct < 12; ++ct) {
        int proto = ct * 16 + lane15;
        if (proto < NPROTO) {
            int kc = proto / 10;
            int m = proto - kc * 10;
            int obase = m * 19 + kc;
            #pragma unroll
            for (int rt = 0; rt < 2; ++rt) {
                int pixbase = n0 + wave * 32 + rt * 16 + quad * 4;
                #pragma unroll
                for (int r = 0; r < 4; ++r)
                    out[(size_t)(pixbase + r) * 190 + obase] = acc[rt][ct][r];
            }
        }
    }
}

// ------------------------------------------------------------------
// per-pixel: s=max_m sim, pred=argmax_k (first-tie), tie flagging,
// e = exp(sim[:,gt]/eps), accumulate E[k][m] and class counts
__global__ void reduce_pred(const float* __restrict__ sim,
                            const int* __restrict__ gt_seg,
                            float* __restrict__ out_pred,
                            float* __restrict__ epix,
                            float* __restrict__ E,
                            float* __restrict__ cnt,
                            int* __restrict__ tiecnt,
                            int* __restrict__ tielist) {
    __shared__ float Ek[192];
    __shared__ float hist[20];
    int tid = threadIdx.x;
    if (tid < 192) Ek[tid] = 0.f;
    if (tid < 20) hist[tid] = 0.f;
    __syncthreads();
    int n = blockIdx.x * 256 + tid;
    const float* row = sim + (size_t)n * 190;
    const float2* rp2 = reinterpret_cast<const float2*>(row);
    float s[19];
    #pragma unroll
    for (int k = 0; k < 19; ++k) s[k] = -1e30f;
    #pragma unroll
    for (int i = 0; i < 95; ++i) {
        float2 d = rp2[i];
        s[(2 * i) % 19]     = fmaxf(s[(2 * i) % 19], d.x);
        s[(2 * i + 1) % 19] = fmaxf(s[(2 * i + 1) % 19], d.y);
    }
    float best = s[0], second = -1e30f;
    int bk = 0;
    #pragma unroll
    for (int k = 1; k < 19; ++k) {
        float v = s[k];
        if (v > best) { second = best; best = v; bk = k; }
        else if (v > second) second = v;
    }
    out_pred[n] = (float)bk;
    if (best - second < 3e-4f) {
        int pos = atomicAdd(tiecnt, 1);
        if (pos < N_PIX) tielist[pos] = n;
    }
    int g = gt_seg[n];
    #pragma unroll
    for (int m = 0; m < 10; ++m) {
        float ev = __expf(row[m * 19 + g] * 20.f);
        epix[(size_t)n * 10 + m] = ev;
        atomicAdd(&Ek[g * 10 + m], ev);
    }
    atomicAdd(&hist[g], 1.f);
    __syncthreads();
    if (tid < 190) atomicAdd(&E[tid], Ek[tid]);
    if (tid < 19) atomicAdd(&cnt[tid], hist[tid]);
}

// ------------------------------------------------------------------
// fp64 recompute of argmax for near-tie pixels
__global__ void tiefix(const float* __restrict__ x,
                       const float4* __restrict__ pscale,
                       const float* __restrict__ gamma,
                       const float* __restrict__ beta,
                       const float* __restrict__ pf32,
                       const int* __restrict__ tiecnt,
                       const int* __restrict__ tielist,
                       float* __restrict__ out_pred) {
    __shared__ float xrow[720];
    __shared__ double sd[190];
    int count = *tiecnt;
    if (count > N_PIX) count = N_PIX;
    int wave = threadIdx.x >> 6, lane = threadIdx.x & 63;
    for (int it = blockIdx.x; it < count; it += gridDim.x) {
        int n = tielist[it];
        float4 sc = pscale[n];
        for (int c = threadIdx.x; c < 720; c += 256)
            xrow[c] = (sc.x * x[(size_t)n * 720 + c] + sc.y) * gamma[c] + sc.z * beta[c];
        __syncthreads();
        for (int p = wave; p < NPROTO; p += 4) {
            const float* pr = pf32 + (size_t)p * 720;
            double a = 0.0;
            for (int j = 0; j < 12; ++j) {
                int i = lane + 64 * j;
                if (i < 720) a += (double)xrow[i] * (double)pr[i];
            }
            #pragma unroll
            for (int m = 1; m < 64; m <<= 1) a += __shfl_xor(a, m);
            if (lane == 0) sd[p] = a;
        }
        __syncthreads();
        if (threadIdx.x == 0) {
            double best = -1e300;
            int bk = 0;
            for (int k = 0; k < 19; ++k) {
                double sk = -1e300;
                for (int m = 0; m < 10; ++m) sk = fmax(sk, sd[k * 10 + m]);
                if (sk > best) { best = sk; bk = k; }
            }
            out_pred[n] = (float)bk;
        }
        __syncthreads();
    }
}

// ------------------------------------------------------------------
// Sinkhorn small kernels. v1: from E (col-normalize iter 1)
__global__ void v1k(const float* __restrict__ E, float* __restrict__ v) {
    __shared__ float Es[192];
    int t = threadIdx.x;
    if (t < 192) Es[t] = (t < 190) ? E[t] : 0.f;
    __syncthreads();
    if (t < 190) {
        int k = t / 10;
        float S = 0.f;
        #pragma unroll
        for (int m = 0; m < 10; ++m) S += Es[k * 10 + m];
        float v0 = 1.f / fmaxf(S, 1e-12f);
        float r = v0 * Es[t];
        v[t] = v0 / (fmaxf(r, 1e-12f) * 10.f);
    }
}

__global__ void v23k(float* __restrict__ v, const float* __restrict__ G) {
    int t = threadIdx.x;
    if (t < 190) {
        float r = v[t] * G[t];
        v[t] = v[t] / (fmaxf(r, 1e-12f) * 10.f);
    }
}

// row-normalize pass: u update + accumulate G = sum(e*u) for next col pass
__global__ void pk(const float* __restrict__ epix,
                   const int* __restrict__ gt_seg,
                   const float* __restrict__ v,
                   const float* __restrict__ cnt,
                   const float* __restrict__ uin,
                   float* __restrict__ uout,
                   float* __restrict__ G) {
    __shared__ float vs[190];
    __shared__ float cs[19];
    __shared__ float Ga[190];
    int tid = threadIdx.x;
    if (tid < 190) { vs[tid] = v[tid]; Ga[tid] = 0.f; }
    if (tid < 19) cs[tid] = cnt[tid];
    __syncthreads();
    int n = blockIdx.x * 256 + tid;
    int g = gt_seg[n];
    float ns = fmaxf(cs[g], 1.f);
    const float* e = epix + (size_t)n * 10;
    float ev[10];
    float dot = 0.f;
    #pragma unroll
    for (int m = 0; m < 10; ++m) { ev[m] = e[m]; dot += ev[m] * vs[g * 10 + m]; }
    float up = uin ? uin[n] : 1.f;
    float c = up * dot;
    float u = up / (fmaxf(c, 1e-12f) * ns);
    uout[n] = u;
    #pragma unroll
    for (int m = 0; m < 10; ++m) atomicAdd(&Ga[g * 10 + m], ev[m] * u);
    __syncthreads();
    if (tid < 190) atomicAdd(&G[tid], Ga[tid]);
}

// final row-normalize + q = e*u3*v3*n_safe, zeros elsewhere
__global__ void p3k(const float* __restrict__ epix,
                    const int* __restrict__ gt_seg,
                    const float* __restrict__ v,
                    const float* __restrict__ cnt,
                    const float* __restrict__ uin,
                    float* __restrict__ qout) {
    __shared__ float vs[190];
    __shared__ float cs[19];
    int tid = threadIdx.x;
    if (tid < 190) vs[tid] = v[tid];
    if (tid < 19) cs[tid] = cnt[tid];
    __syncthreads();
    int n = blockIdx.x * 256 + tid;
    int g = gt_seg[n];
    float ns = fmaxf(cs[g], 1.f);
    const float* e = epix + (size_t)n * 10;
    float ev[10];
    float dot = 0.f;
    #pragma unroll
    for (int m = 0; m < 10; ++m) { ev[m] = e[m]; dot += ev[m] * vs[g * 10 + m]; }
    float up = uin[n];
    float c = up * dot;
    float u3 = up / (fmaxf(c, 1e-12f) * ns);
    float2 qv[5];
    #pragma unroll
    for (int j = 0; j < 5; ++j) {
        qv[j].x = ev[2 * j] * u3 * vs[g * 10 + 2 * j] * ns;
        qv[j].y = ev[2 * j + 1] * u3 * vs[g * 10 + 2 * j + 1] * ns;
    }
    const float2 z2 = make_float2(0.f, 0.f);
    for (int k = 0; k < 19; ++k) {
        float2* dst = reinterpret_cast<float2*>(qout + (size_t)k * 655360 + (size_t)n * 10);
        if (k == g) {
            #pragma unroll
            for (int j = 0; j < 5; ++j) dst[j] = qv[j];
        } else {
            #pragma unroll
            for (int j = 0; j < 5; ++j) dst[j] = z2;
        }
    }
}

// ------------------------------------------------------------------
extern "C" void kernel_launch(void* const* d_in, const int* in_sizes, int n_in,
                              void* d_out, int out_size, void* d_ws, size_t ws_size,
                              hipStream_t stream) {
    const float* x      = (const float*)d_in[0];
    const int*   gt     = (const int*)d_in[1];
    const float* gamma  = (const float*)d_in[2];
    const float* beta   = (const float*)d_in[3];
    const float* protos = (const float*)d_in[4];
    float* out = (float*)d_out;
    char* ws = (char*)d_ws;

    float*  E       = (float*)(ws + WS_E);
    float*  G2      = (float*)(ws + WS_G2);
    float*  G3      = (float*)(ws + WS_G3);
    float*  cnt     = (float*)(ws + WS_CNT);
    int*    tiecnt  = (int*)(ws + WS_TIECNT);
    float*  v       = (float*)(ws + WS_V);
    float4* pscale  = (float4*)(ws + WS_PSCALE);
    float*  epix    = (float*)(ws + WS_EPIX);
    float*  u       = (float*)(ws + WS_U);
    int*    tielist = (int*)(ws + WS_TIELIST);
    _Float16* pf16  = (_Float16*)(ws + WS_PF16);
    float*  pf32    = (float*)(ws + WS_PF32);

    zero_acc<<<1, 1024, 0, stream>>>((float*)ws);
    proto_prep<<<192, 256, 0, stream>>>(protos, pf16, pf32);
    stats_kernel<<<16384, 256, 0, stream>>>(x, gamma, beta, pscale);
    gemm_sim<<<512, 256, 0, stream>>>(x, pscale, gamma, beta, pf16, out);
    reduce_pred<<<256, 256, 0, stream>>>(out, gt, out + OFF_PRED, epix, E, cnt, tiecnt, tielist);
    tiefix<<<1024, 256, 0, stream>>>(x, pscale, gamma, beta, pf32, tiecnt, tielist, out + OFF_PRED);
    v1k<<<1, 256, 0, stream>>>(E, v);
    pk<<<256, 256, 0, stream>>>(epix, gt, v, cnt, nullptr, u, G2);
    v23k<<<1, 256, 0, stream>>>(v, G2);
    pk<<<256, 256, 0, stream>>>(epix, gt, v, cnt, u, u, G3);
    v23k<<<1, 256, 0, stream>>>(v, G3);
    p3k<<<256, 256, 0, stream>>>(epix, gt, v, cnt, u, out + OFF_Q);
}

// Round 2
// 523.669 us; speedup vs baseline: 1.2192x; 1.2192x over previous
//
#include <hip/hip_runtime.h>
#include <stdint.h>

#define N_PIX    65536
#define C_DIM    720
#define K_CLS    19
#define M_PROTO  10
#define NPROTO   190
#define CPAD     768
#define OFF_Q    12451840
#define OFF_PRED 24903680

typedef _Float16 half8 __attribute__((ext_vector_type(8)));
typedef float    f32x4 __attribute__((ext_vector_type(4)));

// ---- workspace layout (byte offsets) ----
#define WS_E       0u          // 192 floats
#define WS_G2      768u        // 192 floats
#define WS_G3      1536u       // 192 floats
#define WS_CNT     2304u       // 32 floats
#define WS_TIECNT  2432u       // 1 int
#define WS_V       2560u       // 192 floats
#define WS_PSCALE  4096u       // 65536 * float4
#define WS_EPIX    1052672u    // 65536*10 floats
#define WS_U       3674112u    // 65536 floats
#define WS_TIELIST 3936256u    // 65536 ints
#define WS_PF16    4198400u    // 192*768 half
#define WS_PF32    4493312u    // 190*720 float  (ends 5040512)

// ------------------------------------------------------------------
// zero the small accumulator region (E, G2, G3, cnt, tiecnt)
__global__ void zero_acc(float* ws) {
    if (threadIdx.x < 640) ws[threadIdx.x] = 0.f;
}

// ------------------------------------------------------------------
// L2-normalize prototypes -> f16 padded [192][768] and f32 [190][720]
__global__ void proto_prep(const float* __restrict__ protos,
                           _Float16* __restrict__ pf16,
                           float* __restrict__ pf32) {
    int p = blockIdx.x;
    int tid = threadIdx.x;
    if (p >= NPROTO) {   // padding rows 190,191 -> zeros
        for (int c = tid; c < CPAD; c += 256) pf16[(size_t)p * CPAD + c] = (_Float16)0.f;
        return;
    }
    __shared__ float red[256];
    const float* row = protos + (size_t)p * C_DIM;
    float ss = 0.f;
    for (int c = tid; c < C_DIM; c += 256) { float v = row[c]; ss += v * v; }
    red[tid] = ss;
    __syncthreads();
    for (int s = 128; s > 0; s >>= 1) {
        if (tid < s) red[tid] += red[tid + s];
        __syncthreads();
    }
    float invn = 1.f / fmaxf(sqrtf(red[0]), 1e-12f);
    for (int c = tid; c < CPAD; c += 256) {
        float v = (c < C_DIM) ? row[c] * invn : 0.f;
        pf16[(size_t)p * CPAD + c] = (_Float16)v;
        if (c < C_DIM) pf32[(size_t)p * C_DIM + c] = v;
    }
}

// ------------------------------------------------------------------
// LayerNorm + L2-norm statistics: per-pixel scalars (p, q, rn) such that
// xn_i = (p*x_i + q)*g_i + rn*b_i
__global__ void stats_kernel(const float* __restrict__ x,
                             const float* __restrict__ gamma,
                             const float* __restrict__ beta,
                             float4* __restrict__ pscale) {
    int wave = threadIdx.x >> 6, lane = threadIdx.x & 63;
    int n = blockIdx.x * 4 + wave;
    const float* row = x + (size_t)n * C_DIM;
    float a[8];
    #pragma unroll
    for (int t = 0; t < 8; ++t) a[t] = 0.f;
    #pragma unroll
    for (int j = 0; j < 12; ++j) {
        int i = lane + 64 * j;
        if (i < C_DIM) {
            float v = row[i], g = gamma[i], b = beta[i];
            float g2 = g * g;
            a[0] += v;          a[1] += v * v;
            a[2] += v * g2;     a[3] += v * v * g2;
            a[4] += v * g * b;  a[5] += g2;
            a[6] += g * b;      a[7] += b * b;
        }
    }
    #pragma unroll
    for (int m = 1; m < 64; m <<= 1) {
        #pragma unroll
        for (int t = 0; t < 8; ++t) a[t] += __shfl_xor(a[t], m);
    }
    if (lane == 0) {
        float mu   = a[0] * (1.f / 720.f);
        float var  = a[1] * (1.f / 720.f) - mu * mu;
        float rsig = rsqrtf(var + 1e-5f);
        float ny2  = rsig * rsig * (a[3] - 2.f * mu * a[2] + mu * mu * a[5])
                   + 2.f * rsig * (a[4] - mu * a[6]) + a[7];
        float rn   = 1.f / fmaxf(sqrtf(fmaxf(ny2, 0.f)), 1e-12f);
        float pp   = rsig * rn;
        pscale[n]  = make_float4(pp, -pp * mu, rn, 0.f);
    }
}

// ------------------------------------------------------------------
// Fused LN-apply + f16 MFMA GEMM: sim[n][m][k] = xn . protosN^T
// 64-pixel tile per block (grid 1024 -> 4 blocks/CU), wave = 16 pixels x 192 protos
// Epilogue transposed through LDS -> coalesced 190-float row writes.
__global__ __launch_bounds__(256) void gemm_sim(
        const float*  __restrict__ x,
        const float4* __restrict__ pscale,
        const float*  __restrict__ gamma,
        const float*  __restrict__ beta,
        const _Float16* __restrict__ pf16,
        float* __restrict__ out) {
    __shared__ __align__(16) char smem[36864];
    _Float16* xs = (_Float16*)smem;            // [64][72]
    _Float16* ps = (_Float16*)(smem + 9216);   // [192][72]

    int tid = threadIdx.x;
    int wave = tid >> 6, lane = tid & 63;
    int lane15 = lane & 15, quad = lane >> 4;
    int n0 = blockIdx.x * 64;

    f32x4 acc[12];
    #pragma unroll
    for (int ct = 0; ct < 12; ++ct)
        acc[ct] = (f32x4){0.f, 0.f, 0.f, 0.f};

    #pragma unroll 1
    for (int ch = 0; ch < 12; ++ch) {
        __syncthreads();
        int kb4 = ch * 16;  // float4 index base within the 180 valid float4s
        // stage x (convert to normalized f16 on the fly): 64 rows x 16 float4
        #pragma unroll
        for (int i = 0; i < 4; ++i) {
            int idx = tid + 256 * i;
            int r = idx >> 4, c4 = idx & 15;
            int gc4 = kb4 + c4;
            float4 xv = make_float4(0.f, 0.f, 0.f, 0.f);
            float4 gv = xv, bv = xv;
            if (gc4 < 180) {
                xv = *(const float4*)(x + (size_t)(n0 + r) * C_DIM + gc4 * 4);
                gv = *(const float4*)(gamma + gc4 * 4);
                bv = *(const float4*)(beta + gc4 * 4);
            }
            float4 sc = pscale[n0 + r];
            union { _Float16 h[4]; uint2 u; } cv;
            cv.h[0] = (_Float16)((sc.x * xv.x + sc.y) * gv.x + sc.z * bv.x);
            cv.h[1] = (_Float16)((sc.x * xv.y + sc.y) * gv.y + sc.z * bv.y);
            cv.h[2] = (_Float16)((sc.x * xv.z + sc.y) * gv.z + sc.z * bv.z);
            cv.h[3] = (_Float16)((sc.x * xv.w + sc.y) * gv.w + sc.z * bv.w);
            *reinterpret_cast<uint2*>(&xs[r * 72 + c4 * 4]) = cv.u;
        }
        // stage protos (already f16, padded rows 190/191 are zero)
        #pragma unroll
        for (int i = 0; i < 6; ++i) {
            int idx = tid + 256 * i;
            int r = idx >> 3, c8 = idx & 7;
            int4 v = *(const int4*)(pf16 + (size_t)r * CPAD + ch * 64 + c8 * 8);
            *reinterpret_cast<int4*>(&ps[r * 72 + c8 * 8]) = v;
        }
        __syncthreads();
        #pragma unroll
        for (int ks = 0; ks < 2; ++ks) {
            int col = ks * 32 + quad * 8;
            half8 a0 = *reinterpret_cast<const half8*>(&xs[(wave * 16 + lane15) * 72 + col]);
            half8 b[12];
            #pragma unroll
            for (int ct = 0; ct < 12; ++ct)
                b[ct] = *reinterpret_cast<const half8*>(&ps[(ct * 16 + lane15) * 72 + col]);
            #pragma unroll
            for (int ct = 0; ct < 12; ++ct)
                acc[ct] = __builtin_amdgcn_mfma_f32_16x16x32_f16(a0, b[ct], acc[ct], 0, 0, 0);
        }
    }

    // ---- epilogue: transpose through LDS, write coalesced rows ----
    // C/D layout: proto = ct*16 + (lane&15), pixel_local = quad*4 + r
    __syncthreads();                    // done reading xs/ps
    float* ebuf = (float*)smem + wave * 1600;   // per-wave [8][200]
    #pragma unroll
    for (int h = 0; h < 2; ++h) {
        if ((quad >> 1) == h) {
            int prow = (quad - 2 * h) * 4;      // 0 or 4
            #pragma unroll
            for (int ct = 0; ct < 12; ++ct) {
                int proto = ct * 16 + lane15;
                if (proto < NPROTO) {
                    int kc = proto / 10;
                    int m = proto - kc * 10;
                    int obase = m * 19 + kc;
                    #pragma unroll
                    for (int r = 0; r < 4; ++r)
                        ebuf[(prow + r) * 200 + obase] = acc[ct][r];
                }
            }
        }
        __syncthreads();
        #pragma unroll
        for (int p = 0; p < 8; ++p) {
            int pixel = n0 + wave * 16 + 8 * h + p;
            #pragma unroll
            for (int j = 0; j < 3; ++j) {
                int col = lane + 64 * j;
                if (col < NPROTO)
                    out[(size_t)pixel * 190 + col] = ebuf[p * 200 + col];
            }
        }
        __syncthreads();
    }
}

// ------------------------------------------------------------------
// per-pixel: s=max_m sim, pred=argmax_k (first-tie), tie flagging,
// e = exp(sim[:,gt]/eps), accumulate E[k][m] and class counts
__global__ void reduce_pred(const float* __restrict__ sim,
                            const int* __restrict__ gt_seg,
                            float* __restrict__ out_pred,
                            float* __restrict__ epix,
                            float* __restrict__ E,
                            float* __restrict__ cnt,
                            int* __restrict__ tiecnt,
                            int* __restrict__ tielist) {
    __shared__ float Ek[192];
    __shared__ float hist[20];
    int tid = threadIdx.x;
    if (tid < 192) Ek[tid] = 0.f;
    if (tid < 20) hist[tid] = 0.f;
    __syncthreads();
    int n = blockIdx.x * 256 + tid;
    const float* row = sim + (size_t)n * 190;
    const float2* rp2 = reinterpret_cast<const float2*>(row);
    float s[19];
    #pragma unroll
    for (int k = 0; k < 19; ++k) s[k] = -1e30f;
    #pragma unroll
    for (int i = 0; i < 95; ++i) {
        float2 d = rp2[i];
        s[(2 * i) % 19]     = fmaxf(s[(2 * i) % 19], d.x);
        s[(2 * i + 1) % 19] = fmaxf(s[(2 * i + 1) % 19], d.y);
    }
    float best = s[0], second = -1e30f;
    int bk = 0;
    #pragma unroll
    for (int k = 1; k < 19; ++k) {
        float v = s[k];
        if (v > best) { second = best; best = v; bk = k; }
        else if (v > second) second = v;
    }
    out_pred[n] = (float)bk;
    if (best - second < 3e-4f) {
        int pos = atomicAdd(tiecnt, 1);
        if (pos < N_PIX) tielist[pos] = n;
    }
    int g = gt_seg[n];
    #pragma unroll
    for (int m = 0; m < 10; ++m) {
        float ev = __expf(row[m * 19 + g] * 20.f);
        epix[(size_t)n * 10 + m] = ev;
        atomicAdd(&Ek[g * 10 + m], ev);
    }
    atomicAdd(&hist[g], 1.f);
    __syncthreads();
    if (tid < 190) atomicAdd(&E[tid], Ek[tid]);
    if (tid < 19) atomicAdd(&cnt[tid], hist[tid]);
}

// ------------------------------------------------------------------
// fp64 recompute of argmax for near-tie pixels
__global__ void tiefix(const float* __restrict__ x,
                       const float4* __restrict__ pscale,
                       const float* __restrict__ gamma,
                       const float* __restrict__ beta,
                       const float* __restrict__ pf32,
                       const int* __restrict__ tiecnt,
                       const int* __restrict__ tielist,
                       float* __restrict__ out_pred) {
    __shared__ float xrow[720];
    __shared__ double sd[190];
    int count = *tiecnt;
    if (count > N_PIX) count = N_PIX;
    int wave = threadIdx.x >> 6, lane = threadIdx.x & 63;
    for (int it = blockIdx.x; it < count; it += gridDim.x) {
        int n = tielist[it];
        float4 sc = pscale[n];
        for (int c = threadIdx.x; c < 720; c += 256)
            xrow[c] = (sc.x * x[(size_t)n * 720 + c] + sc.y) * gamma[c] + sc.z * beta[c];
        __syncthreads();
        for (int p = wave; p < NPROTO; p += 4) {
            const float* pr = pf32 + (size_t)p * 720;
            double a = 0.0;
            for (int j = 0; j < 12; ++j) {
                int i = lane + 64 * j;
                if (i < 720) a += (double)xrow[i] * (double)pr[i];
            }
            #pragma unroll
            for (int m = 1; m < 64; m <<= 1) a += __shfl_xor(a, m);
            if (lane == 0) sd[p] = a;
        }
        __syncthreads();
        if (threadIdx.x == 0) {
            double best = -1e300;
            int bk = 0;
            for (int k = 0; k < 19; ++k) {
                double sk = -1e300;
                for (int m = 0; m < 10; ++m) sk = fmax(sk, sd[k * 10 + m]);
                if (sk > best) { best = sk; bk = k; }
            }
            out_pred[n] = (float)bk;
        }
        __syncthreads();
    }
}

// ------------------------------------------------------------------
// Sinkhorn small kernels. v1: from E (col-normalize iter 1)
__global__ void v1k(const float* __restrict__ E, float* __restrict__ v) {
    __shared__ float Es[192];
    int t = threadIdx.x;
    if (t < 192) Es[t] = (t < 190) ? E[t] : 0.f;
    __syncthreads();
    if (t < 190) {
        int k = t / 10;
        float S = 0.f;
        #pragma unroll
        for (int m = 0; m < 10; ++m) S += Es[k * 10 + m];
        float v0 = 1.f / fmaxf(S, 1e-12f);
        float r = v0 * Es[t];
        v[t] = v0 / (fmaxf(r, 1e-12f) * 10.f);
    }
}

__global__ void v23k(float* __restrict__ v, const float* __restrict__ G) {
    int t = threadIdx.x;
    if (t < 190) {
        float r = v[t] * G[t];
        v[t] = v[t] / (fmaxf(r, 1e-12f) * 10.f);
    }
}

// row-normalize pass: u update + accumulate G = sum(e*u) for next col pass
__global__ void pk(const float* __restrict__ epix,
                   const int* __restrict__ gt_seg,
                   const float* __restrict__ v,
                   const float* __restrict__ cnt,
                   const float* __restrict__ uin,
                   float* __restrict__ uout,
                   float* __restrict__ G) {
    __shared__ float vs[190];
    __shared__ float cs[19];
    __shared__ float Ga[190];
    int tid = threadIdx.x;
    if (tid < 190) { vs[tid] = v[tid]; Ga[tid] = 0.f; }
    if (tid < 19) cs[tid] = cnt[tid];
    __syncthreads();
    int n = blockIdx.x * 256 + tid;
    int g = gt_seg[n];
    float ns = fmaxf(cs[g], 1.f);
    const float* e = epix + (size_t)n * 10;
    float ev[10];
    float dot = 0.f;
    #pragma unroll
    for (int m = 0; m < 10; ++m) { ev[m] = e[m]; dot += ev[m] * vs[g * 10 + m]; }
    float up = uin ? uin[n] : 1.f;
    float c = up * dot;
    float u = up / (fmaxf(c, 1e-12f) * ns);
    uout[n] = u;
    #pragma unroll
    for (int m = 0; m < 10; ++m) atomicAdd(&Ga[g * 10 + m], ev[m] * u);
    __syncthreads();
    if (tid < 190) atomicAdd(&G[tid], Ga[tid]);
}

// final row-normalize + q = e*u3*v3*n_safe, zeros elsewhere
__global__ void p3k(const float* __restrict__ epix,
                    const int* __restrict__ gt_seg,
                    const float* __restrict__ v,
                    const float* __restrict__ cnt,
                    const float* __restrict__ uin,
                    float* __restrict__ qout) {
    __shared__ float vs[190];
    __shared__ float cs[19];
    int tid = threadIdx.x;
    if (tid < 190) vs[tid] = v[tid];
    if (tid < 19) cs[tid] = cnt[tid];
    __syncthreads();
    int n = blockIdx.x * 256 + tid;
    int g = gt_seg[n];
    float ns = fmaxf(cs[g], 1.f);
    const float* e = epix + (size_t)n * 10;
    float ev[10];
    float dot = 0.f;
    #pragma unroll
    for (int m = 0; m < 10; ++m) { ev[m] = e[m]; dot += ev[m] * vs[g * 10 + m]; }
    float up = uin[n];
    float c = up * dot;
    float u3 = up / (fmaxf(c, 1e-12f) * ns);
    float2 qv[5];
    #pragma unroll
    for (int j = 0; j < 5; ++j) {
        qv[j].x = ev[2 * j] * u3 * vs[g * 10 + 2 * j] * ns;
        qv[j].y = ev[2 * j + 1] * u3 * vs[g * 10 + 2 * j + 1] * ns;
    }
    const float2 z2 = make_float2(0.f, 0.f);
    for (int k = 0; k < 19; ++k) {
        float2* dst = reinterpret_cast<float2*>(qout + (size_t)k * 655360 + (size_t)n * 10);
        if (k == g) {
            #pragma unroll
            for (int j = 0; j < 5; ++j) dst[j] = qv[j];
        } else {
            #pragma unroll
            for (int j = 0; j < 5; ++j) dst[j] = z2;
        }
    }
}

// ------------------------------------------------------------------
extern "C" void kernel_launch(void* const* d_in, const int* in_sizes, int n_in,
                              void* d_out, int out_size, void* d_ws, size_t ws_size,
                              hipStream_t stream) {
    const float* x      = (const float*)d_in[0];
    const int*   gt     = (const int*)d_in[1];
    const float* gamma  = (const float*)d_in[2];
    const float* beta   = (const float*)d_in[3];
    const float* protos = (const float*)d_in[4];
    float* out = (float*)d_out;
    char* ws = (char*)d_ws;

    float*  E       = (float*)(ws + WS_E);
    float*  G2      = (float*)(ws + WS_G2);
    float*  G3      = (float*)(ws + WS_G3);
    float*  cnt     = (float*)(ws + WS_CNT);
    int*    tiecnt  = (int*)(ws + WS_TIECNT);
    float*  v       = (float*)(ws + WS_V);
    float4* pscale  = (float4*)(ws + WS_PSCALE);
    float*  epix    = (float*)(ws + WS_EPIX);
    float*  u       = (float*)(ws + WS_U);
    int*    tielist = (int*)(ws + WS_TIELIST);
    _Float16* pf16  = (_Float16*)(ws + WS_PF16);
    float*  pf32    = (float*)(ws + WS_PF32);

    zero_acc<<<1, 1024, 0, stream>>>((float*)ws);
    proto_prep<<<192, 256, 0, stream>>>(protos, pf16, pf32);
    stats_kernel<<<16384, 256, 0, stream>>>(x, gamma, beta, pscale);
    gemm_sim<<<1024, 256, 0, stream>>>(x, pscale, gamma, beta, pf16, out);
    reduce_pred<<<256, 256, 0, stream>>>(out, gt, out + OFF_PRED, epix, E, cnt, tiecnt, tielist);
    tiefix<<<1024, 256, 0, stream>>>(x, pscale, gamma, beta, pf32, tiecnt, tielist, out + OFF_PRED);
    v1k<<<1, 256, 0, stream>>>(E, v);
    pk<<<256, 256, 0, stream>>>(epix, gt, v, cnt, nullptr, u, G2);
    v23k<<<1, 256, 0, stream>>>(v, G2);
    pk<<<256, 256, 0, stream>>>(epix, gt, v, cnt, u, u, G3);
    v23k<<<1, 256, 0, stream>>>(v, G3);
    p3k<<<256, 256, 0, stream>>>(epix, gt, v, cnt, u, out + OFF_Q);
}

// Round 3
// 496.352 us; speedup vs baseline: 1.2863x; 1.0550x over previous
//
#include <hip/hip_runtime.h>
#include <stdint.h>

#define N_PIX    65536
#define C_DIM    720
#define K_CLS    19
#define M_PROTO  10
#define NPROTO   190
#define CPAD     768
#define OFF_Q    12451840
#define OFF_PRED 24903680

typedef _Float16 half8 __attribute__((ext_vector_type(8)));
typedef float    f32x4 __attribute__((ext_vector_type(4)));

// ---- workspace layout (byte offsets) ----
#define WS_E       0u          // 192 floats
#define WS_G2      768u        // 192 floats
#define WS_G3      1536u       // 192 floats
#define WS_CNT     2304u       // 32 floats
#define WS_TIECNT  2432u       // 1 int
#define WS_V       2560u       // 192 floats
#define WS_PSCALE  4096u       // 65536 * float4
#define WS_EPIX    1052672u    // 65536*10 floats
#define WS_U       3674112u    // 65536 floats
#define WS_TIELIST 3936256u    // 65536 ints
#define WS_PF16    4198400u    // 192*768 half
#define WS_PF32    4493312u    // 190*720 float  (ends 5040512)

// ------------------------------------------------------------------
// zero the small accumulator region (E, G2, G3, cnt, tiecnt)
__global__ void zero_acc(float* ws) {
    if (threadIdx.x < 640) ws[threadIdx.x] = 0.f;
}

// ------------------------------------------------------------------
// L2-normalize prototypes -> f16 padded [192][768] and f32 [190][720]
__global__ void proto_prep(const float* __restrict__ protos,
                           _Float16* __restrict__ pf16,
                           float* __restrict__ pf32) {
    int p = blockIdx.x;
    int tid = threadIdx.x;
    if (p >= NPROTO) {   // padding rows 190,191 -> zeros
        for (int c = tid; c < CPAD; c += 256) pf16[(size_t)p * CPAD + c] = (_Float16)0.f;
        return;
    }
    __shared__ float red[256];
    const float* row = protos + (size_t)p * C_DIM;
    float ss = 0.f;
    for (int c = tid; c < C_DIM; c += 256) { float v = row[c]; ss += v * v; }
    red[tid] = ss;
    __syncthreads();
    for (int s = 128; s > 0; s >>= 1) {
        if (tid < s) red[tid] += red[tid + s];
        __syncthreads();
    }
    float invn = 1.f / fmaxf(sqrtf(red[0]), 1e-12f);
    for (int c = tid; c < CPAD; c += 256) {
        float v = (c < C_DIM) ? row[c] * invn : 0.f;
        pf16[(size_t)p * CPAD + c] = (_Float16)v;
        if (c < C_DIM) pf32[(size_t)p * C_DIM + c] = v;
    }
}

// ------------------------------------------------------------------
// LayerNorm + L2-norm statistics: per-pixel scalars (p, q, rn) such that
// xn_i = (p*x_i + q)*g_i + rn*b_i
__global__ void stats_kernel(const float* __restrict__ x,
                             const float* __restrict__ gamma,
                             const float* __restrict__ beta,
                             float4* __restrict__ pscale) {
    int wave = threadIdx.x >> 6, lane = threadIdx.x & 63;
    int n = blockIdx.x * 4 + wave;
    const float* row = x + (size_t)n * C_DIM;
    float a[8];
    #pragma unroll
    for (int t = 0; t < 8; ++t) a[t] = 0.f;
    #pragma unroll
    for (int j = 0; j < 12; ++j) {
        int i = lane + 64 * j;
        if (i < C_DIM) {
            float v = row[i], g = gamma[i], b = beta[i];
            float g2 = g * g;
            a[0] += v;          a[1] += v * v;
            a[2] += v * g2;     a[3] += v * v * g2;
            a[4] += v * g * b;  a[5] += g2;
            a[6] += g * b;      a[7] += b * b;
        }
    }
    #pragma unroll
    for (int m = 1; m < 64; m <<= 1) {
        #pragma unroll
        for (int t = 0; t < 8; ++t) a[t] += __shfl_xor(a[t], m);
    }
    if (lane == 0) {
        float mu   = a[0] * (1.f / 720.f);
        float var  = a[1] * (1.f / 720.f) - mu * mu;
        float rsig = rsqrtf(var + 1e-5f);
        float ny2  = rsig * rsig * (a[3] - 2.f * mu * a[2] + mu * mu * a[5])
                   + 2.f * rsig * (a[4] - mu * a[6]) + a[7];
        float rn   = 1.f / fmaxf(sqrtf(fmaxf(ny2, 0.f)), 1e-12f);
        float pp   = rsig * rn;
        pscale[n]  = make_float4(pp, -pp * mu, rn, 0.f);
    }
}

// ------------------------------------------------------------------
// Fused LN-apply + f16 MFMA GEMM + per-pixel reduction epilogue.
// 64-pixel tile per block (grid 1024), wave = 16 pixels x 192 protos.
// Epilogue: acc -> LDS transpose -> coalesced sim writes, then (fused,
// reading the same LDS) per-pixel max/argmax/tie, e=exp(sim/eps), and
// block-level E/cnt accumulation flushed with one atomic set per block.
__global__ __launch_bounds__(256) void gemm_sim(
        const float*  __restrict__ x,
        const float4* __restrict__ pscale,
        const float*  __restrict__ gamma,
        const float*  __restrict__ beta,
        const _Float16* __restrict__ pf16,
        const int*    __restrict__ gt_seg,
        float* __restrict__ out_sim,
        float* __restrict__ out_pred,
        float* __restrict__ epix,
        float* __restrict__ E,
        float* __restrict__ cnt,
        int*   __restrict__ tiecnt,
        int*   __restrict__ tielist) {
    __shared__ __align__(16) char smem[36864];
    _Float16* xs = (_Float16*)smem;            // [64][72]
    _Float16* ps = (_Float16*)(smem + 9216);   // [192][72]

    int tid = threadIdx.x;
    int wave = tid >> 6, lane = tid & 63;
    int lane15 = lane & 15, quad = lane >> 4;
    int n0 = blockIdx.x * 64;

    f32x4 acc[12];
    #pragma unroll
    for (int ct = 0; ct < 12; ++ct)
        acc[ct] = (f32x4){0.f, 0.f, 0.f, 0.f};

    #pragma unroll 1
    for (int ch = 0; ch < 12; ++ch) {
        __syncthreads();
        int kb4 = ch * 16;  // float4 index base within the 180 valid float4s
        // stage x (convert to normalized f16 on the fly): 64 rows x 16 float4
        #pragma unroll
        for (int i = 0; i < 4; ++i) {
            int idx = tid + 256 * i;
            int r = idx >> 4, c4 = idx & 15;
            int gc4 = kb4 + c4;
            float4 xv = make_float4(0.f, 0.f, 0.f, 0.f);
            float4 gv = xv, bv = xv;
            if (gc4 < 180) {
                xv = *(const float4*)(x + (size_t)(n0 + r) * C_DIM + gc4 * 4);
                gv = *(const float4*)(gamma + gc4 * 4);
                bv = *(const float4*)(beta + gc4 * 4);
            }
            float4 sc = pscale[n0 + r];
            union { _Float16 h[4]; uint2 u; } cv;
            cv.h[0] = (_Float16)((sc.x * xv.x + sc.y) * gv.x + sc.z * bv.x);
            cv.h[1] = (_Float16)((sc.x * xv.y + sc.y) * gv.y + sc.z * bv.y);
            cv.h[2] = (_Float16)((sc.x * xv.z + sc.y) * gv.z + sc.z * bv.z);
            cv.h[3] = (_Float16)((sc.x * xv.w + sc.y) * gv.w + sc.z * bv.w);
            *reinterpret_cast<uint2*>(&xs[r * 72 + c4 * 4]) = cv.u;
        }
        // stage protos (already f16, padded rows 190/191 are zero)
        #pragma unroll
        for (int i = 0; i < 6; ++i) {
            int idx = tid + 256 * i;
            int r = idx >> 3, c8 = idx & 7;
            int4 v = *(const int4*)(pf16 + (size_t)r * CPAD + ch * 64 + c8 * 8);
            *reinterpret_cast<int4*>(&ps[r * 72 + c8 * 8]) = v;
        }
        __syncthreads();
        #pragma unroll
        for (int ks = 0; ks < 2; ++ks) {
            int col = ks * 32 + quad * 8;
            half8 a0 = *reinterpret_cast<const half8*>(&xs[(wave * 16 + lane15) * 72 + col]);
            half8 b[12];
            #pragma unroll
            for (int ct = 0; ct < 12; ++ct)
                b[ct] = *reinterpret_cast<const half8*>(&ps[(ct * 16 + lane15) * 72 + col]);
            #pragma unroll
            for (int ct = 0; ct < 12; ++ct)
                acc[ct] = __builtin_amdgcn_mfma_f32_16x16x32_f16(a0, b[ct], acc[ct], 0, 0, 0);
        }
    }

    // ---- fused epilogue ----
    // LDS reuse: ebuf 4x[8][200] floats (0..6400), smax 4x[152] (6400..7008),
    // Ek [192] (7008..7200), hist [20] (7200..7220)
    __syncthreads();                    // done reading xs/ps
    float* fsm   = (float*)smem;
    float* ebuf  = fsm + wave * 1600;
    float* smaxw = fsm + 6400 + wave * 152;
    float* Eks   = fsm + 7008;
    float* hists = fsm + 7200;
    if (tid < 212) fsm[7008 + tid] = 0.f;
    __syncthreads();

    #pragma unroll
    for (int h = 0; h < 2; ++h) {
        // scatter this half's accumulators into the per-wave transpose buffer
        if ((quad >> 1) == h) {
            int prow = (quad - 2 * h) * 4;      // 0 or 4
            #pragma unroll
            for (int ct = 0; ct < 12; ++ct) {
                int proto = ct * 16 + lane15;
                if (proto < NPROTO) {
                    int kc = proto / 10;
                    int m = proto - kc * 10;
                    int obase = m * 19 + kc;
                    #pragma unroll
                    for (int r = 0; r < 4; ++r)
                        ebuf[(prow + r) * 200 + obase] = acc[ct][r];
                }
            }
        }
        __syncthreads();
        // coalesced sim row writes
        #pragma unroll
        for (int p = 0; p < 8; ++p) {
            int pixel = n0 + wave * 16 + 8 * h + p;
            #pragma unroll
            for (int j = 0; j < 3; ++j) {
                int col = lane + 64 * j;
                if (col < NPROTO)
                    out_sim[(size_t)pixel * 190 + col] = ebuf[p * 200 + col];
            }
        }
        // per-(pixel,class) max over the 10 prototypes
        #pragma unroll
        for (int t = lane; t < 152; t += 64) {
            int p = t / 19, k = t - p * 19;
            const float* row = ebuf + p * 200;
            float mx = row[k];
            #pragma unroll
            for (int m = 1; m < 10; ++m) mx = fmaxf(mx, row[m * 19 + k]);
            smaxw[t] = mx;
        }
        __syncthreads();
        // per-pixel argmax + tie + e-values (8 lanes per wave, one pixel each)
        if (lane < 8) {
            int p = lane;
            int pixel = n0 + wave * 16 + 8 * h + p;
            float best = smaxw[p * 19], second = -1e30f;
            int bk = 0;
            #pragma unroll
            for (int k = 1; k < 19; ++k) {
                float v = smaxw[p * 19 + k];
                if (v > best) { second = best; best = v; bk = k; }
                else if (v > second) second = v;
            }
            out_pred[pixel] = (float)bk;
            if (best - second < 3e-4f) {
                int pos = atomicAdd(tiecnt, 1);
                if (pos < N_PIX) tielist[pos] = pixel;
            }
            int g = gt_seg[pixel];
            atomicAdd(&hists[g], 1.f);
            const float* row = ebuf + p * 200;
            #pragma unroll
            for (int m = 0; m < 10; ++m) {
                float ev = __expf(row[m * 19 + g] * 20.f);
                epix[(size_t)pixel * 10 + m] = ev;
                atomicAdd(&Eks[g * 10 + m], ev);
            }
        }
        __syncthreads();
    }
    // flush block-level accumulators
    if (tid < 190) atomicAdd(&E[tid], Eks[tid]);
    if (tid < 19)  atomicAdd(&cnt[tid], hists[tid]);
}

// ------------------------------------------------------------------
// fp64 recompute of argmax for near-tie pixels
__global__ void tiefix(const float* __restrict__ x,
                       const float4* __restrict__ pscale,
                       const float* __restrict__ gamma,
                       const float* __restrict__ beta,
                       const float* __restrict__ pf32,
                       const int* __restrict__ tiecnt,
                       const int* __restrict__ tielist,
                       float* __restrict__ out_pred) {
    __shared__ float xrow[720];
    __shared__ double sd[190];
    int count = *tiecnt;
    if (count > N_PIX) count = N_PIX;
    int wave = threadIdx.x >> 6, lane = threadIdx.x & 63;
    for (int it = blockIdx.x; it < count; it += gridDim.x) {
        int n = tielist[it];
        float4 sc = pscale[n];
        for (int c = threadIdx.x; c < 720; c += 256)
            xrow[c] = (sc.x * x[(size_t)n * 720 + c] + sc.y) * gamma[c] + sc.z * beta[c];
        __syncthreads();
        for (int p = wave; p < NPROTO; p += 4) {
            const float* pr = pf32 + (size_t)p * 720;
            double a = 0.0;
            for (int j = 0; j < 12; ++j) {
                int i = lane + 64 * j;
                if (i < 720) a += (double)xrow[i] * (double)pr[i];
            }
            #pragma unroll
            for (int m = 1; m < 64; m <<= 1) a += __shfl_xor(a, m);
            if (lane == 0) sd[p] = a;
        }
        __syncthreads();
        if (threadIdx.x == 0) {
            double best = -1e300;
            int bk = 0;
            for (int k = 0; k < 19; ++k) {
                double sk = -1e300;
                for (int m = 0; m < 10; ++m) sk = fmax(sk, sd[k * 10 + m]);
                if (sk > best) { best = sk; bk = k; }
            }
            out_pred[n] = (float)bk;
        }
        __syncthreads();
    }
}

// ------------------------------------------------------------------
// Sinkhorn small kernels. v1: from E (col-normalize iter 1)
__global__ void v1k(const float* __restrict__ E, float* __restrict__ v) {
    __shared__ float Es[192];
    int t = threadIdx.x;
    if (t < 192) Es[t] = (t < 190) ? E[t] : 0.f;
    __syncthreads();
    if (t < 190) {
        int k = t / 10;
        float S = 0.f;
        #pragma unroll
        for (int m = 0; m < 10; ++m) S += Es[k * 10 + m];
        float v0 = 1.f / fmaxf(S, 1e-12f);
        float r = v0 * Es[t];
        v[t] = v0 / (fmaxf(r, 1e-12f) * 10.f);
    }
}

__global__ void v23k(float* __restrict__ v, const float* __restrict__ G) {
    int t = threadIdx.x;
    if (t < 190) {
        float r = v[t] * G[t];
        v[t] = v[t] / (fmaxf(r, 1e-12f) * 10.f);
    }
}

// row-normalize pass: u update + accumulate G = sum(e*u) for next col pass
__global__ void pk(const float* __restrict__ epix,
                   const int* __restrict__ gt_seg,
                   const float* __restrict__ v,
                   const float* __restrict__ cnt,
                   const float* __restrict__ uin,
                   float* __restrict__ uout,
                   float* __restrict__ G) {
    __shared__ float vs[190];
    __shared__ float cs[19];
    __shared__ float Ga[190];
    int tid = threadIdx.x;
    if (tid < 190) { vs[tid] = v[tid]; Ga[tid] = 0.f; }
    if (tid < 19) cs[tid] = cnt[tid];
    __syncthreads();
    int n = blockIdx.x * 256 + tid;
    int g = gt_seg[n];
    float ns = fmaxf(cs[g], 1.f);
    const float* e = epix + (size_t)n * 10;
    float ev[10];
    float dot = 0.f;
    #pragma unroll
    for (int m = 0; m < 10; ++m) { ev[m] = e[m]; dot += ev[m] * vs[g * 10 + m]; }
    float up = uin ? uin[n] : 1.f;
    float c = up * dot;
    float u = up / (fmaxf(c, 1e-12f) * ns);
    uout[n] = u;
    #pragma unroll
    for (int m = 0; m < 10; ++m) atomicAdd(&Ga[g * 10 + m], ev[m] * u);
    __syncthreads();
    if (tid < 190) atomicAdd(&G[tid], Ga[tid]);
}

// final row-normalize + q = e*u3*v3*n_safe, zeros elsewhere
__global__ void p3k(const float* __restrict__ epix,
                    const int* __restrict__ gt_seg,
                    const float* __restrict__ v,
                    const float* __restrict__ cnt,
                    const float* __restrict__ uin,
                    float* __restrict__ qout) {
    __shared__ float vs[190];
    __shared__ float cs[19];
    int tid = threadIdx.x;
    if (tid < 190) vs[tid] = v[tid];
    if (tid < 19) cs[tid] = cnt[tid];
    __syncthreads();
    int n = blockIdx.x * 256 + tid;
    int g = gt_seg[n];
    float ns = fmaxf(cs[g], 1.f);
    const float* e = epix + (size_t)n * 10;
    float ev[10];
    float dot = 0.f;
    #pragma unroll
    for (int m = 0; m < 10; ++m) { ev[m] = e[m]; dot += ev[m] * vs[g * 10 + m]; }
    float up = uin[n];
    float c = up * dot;
    float u3 = up / (fmaxf(c, 1e-12f) * ns);
    float2 qv[5];
    #pragma unroll
    for (int j = 0; j < 5; ++j) {
        qv[j].x = ev[2 * j] * u3 * vs[g * 10 + 2 * j] * ns;
        qv[j].y = ev[2 * j + 1] * u3 * vs[g * 10 + 2 * j + 1] * ns;
    }
    const float2 z2 = make_float2(0.f, 0.f);
    for (int k = 0; k < 19; ++k) {
        float2* dst = reinterpret_cast<float2*>(qout + (size_t)k * 655360 + (size_t)n * 10);
        if (k == g) {
            #pragma unroll
            for (int j = 0; j < 5; ++j) dst[j] = qv[j];
        } else {
            #pragma unroll
            for (int j = 0; j < 5; ++j) dst[j] = z2;
        }
    }
}

// ------------------------------------------------------------------
extern "C" void kernel_launch(void* const* d_in, const int* in_sizes, int n_in,
                              void* d_out, int out_size, void* d_ws, size_t ws_size,
                              hipStream_t stream) {
    const float* x      = (const float*)d_in[0];
    const int*   gt     = (const int*)d_in[1];
    const float* gamma  = (const float*)d_in[2];
    const float* beta   = (const float*)d_in[3];
    const float* protos = (const float*)d_in[4];
    float* out = (float*)d_out;
    char* ws = (char*)d_ws;

    float*  E       = (float*)(ws + WS_E);
    float*  G2      = (float*)(ws + WS_G2);
    float*  G3      = (float*)(ws + WS_G3);
    float*  cnt     = (float*)(ws + WS_CNT);
    int*    tiecnt  = (int*)(ws + WS_TIECNT);
    float*  v       = (float*)(ws + WS_V);
    float4* pscale  = (float4*)(ws + WS_PSCALE);
    float*  epix    = (float*)(ws + WS_EPIX);
    float*  u       = (float*)(ws + WS_U);
    int*    tielist = (int*)(ws + WS_TIELIST);
    _Float16* pf16  = (_Float16*)(ws + WS_PF16);
    float*  pf32    = (float*)(ws + WS_PF32);

    zero_acc<<<1, 1024, 0, stream>>>((float*)ws);
    proto_prep<<<192, 256, 0, stream>>>(protos, pf16, pf32);
    stats_kernel<<<16384, 256, 0, stream>>>(x, gamma, beta, pscale);
    gemm_sim<<<1024, 256, 0, stream>>>(x, pscale, gamma, beta, pf16, gt,
                                       out, out + OFF_PRED, epix, E, cnt, tiecnt, tielist);
    tiefix<<<1024, 256, 0, stream>>>(x, pscale, gamma, beta, pf32, tiecnt, tielist, out + OFF_PRED);
    v1k<<<1, 256, 0, stream>>>(E, v);
    pk<<<256, 256, 0, stream>>>(epix, gt, v, cnt, nullptr, u, G2);
    v23k<<<1, 256, 0, stream>>>(v, G2);
    pk<<<256, 256, 0, stream>>>(epix, gt, v, cnt, u, u, G3);
    v23k<<<1, 256, 0, stream>>>(v, G3);
    p3k<<<256, 256, 0, stream>>>(epix, gt, v, cnt, u, out + OFF_Q);
}